// Round 1
// baseline (1361.090 us; speedup 1.0000x reference)
//
#include <hip/hip_runtime.h>
#include <hip/hip_bf16.h>

typedef __bf16 bf16x8 __attribute__((ext_vector_type(8)));
typedef float f32x4 __attribute__((ext_vector_type(4)));

#define M_DIM 8192
#define K_DIM 4096
#define N_DIM 11008
#define KW 512      // K/8 ints per qweight row
#define NG 32

#define BM 128
#define BN 128
#define BK 64
#define KSTEPS (K_DIM / BK)   // 64

__global__ __launch_bounds__(256) void TurboQuantLinear_gemm_dq(
    const float* __restrict__ x,
    const unsigned int* __restrict__ qw,
    const float* __restrict__ scales,
    const int* __restrict__ qzeros,
    float* __restrict__ out)
{
    // bf16 tiles, 16B-slot XOR swizzle: slot' = slot ^ (row&7)
    __shared__ __bf16 As[BM * BK];   // 16 KiB
    __shared__ __bf16 Bs[BN * BK];   // 16 KiB

    const int t    = threadIdx.x;
    const int lane = t & 63;
    const int wave = t >> 6;
    const int wr   = wave >> 1;      // wave row (0..1) -> 64-row band of M
    const int wc   = wave & 1;       // wave col (0..1) -> 64-col band of N

    const int m0 = blockIdx.x * BM;  // 64 blocks
    const int n0 = blockIdx.y * BN;  // 86 blocks

    f32x4 acc[4][4] = {};

    for (int kt = 0; kt < KSTEPS; ++kt) {
        const int k0 = kt * BK;
        const int g  = k0 >> 7;          // quant group (128-wide): constant per K-step

        // ---- stage A: 128x64 fp32 -> bf16 (4 octets of 8 floats per thread) ----
        #pragma unroll
        for (int i = 0; i < 4; ++i) {
            int o  = t + i * 256;
            int r  = o >> 3;             // row in tile (0..127)
            int c8 = o & 7;              // 8-float octet within row
            const float4* src = reinterpret_cast<const float4*>(
                &x[(size_t)(m0 + r) * K_DIM + k0 + c8 * 8]);
            float4 f0 = src[0];
            float4 f1 = src[1];
            bf16x8 v;
            v[0] = (__bf16)f0.x; v[1] = (__bf16)f0.y; v[2] = (__bf16)f0.z; v[3] = (__bf16)f0.w;
            v[4] = (__bf16)f1.x; v[5] = (__bf16)f1.y; v[6] = (__bf16)f1.z; v[7] = (__bf16)f1.w;
            int slot = c8 ^ (r & 7);
            *reinterpret_cast<bf16x8*>(&As[r * BK + slot * 8]) = v;
        }

        // ---- stage B: dequant 128x64 int4 -> bf16 (4 int32 per thread) ----
        const int kw0 = kt * 8;
        #pragma unroll
        for (int i = 0; i < 4; ++i) {
            int idx = t + i * 256;
            int r   = idx >> 3;          // output-col row of tile (0..127)
            int w   = idx & 7;           // int32 within K-step
            unsigned int q = qw[(size_t)(n0 + r) * KW + kw0 + w];
            float s  = scales[(n0 + r) * NG + g];
            float z  = (float)qzeros[(n0 + r) * NG + g];
            float zs = z * s;
            bf16x8 v;
            #pragma unroll
            for (int j = 0; j < 8; ++j) {
                float val = (float)((q >> (4 * j)) & 15u) * s - zs;
                v[j] = (__bf16)val;
            }
            int slot = w ^ (r & 7);
            *reinterpret_cast<bf16x8*>(&Bs[r * BK + slot * 8]) = v;
        }

        __syncthreads();

        // ---- MFMA: each wave 4x4 fragments of 16x16, two k=32 sub-steps ----
        const int row_in_l = lane & 15;
        #pragma unroll
        for (int kk = 0; kk < 2; ++kk) {
            const int kslot = kk * 4 + (lane >> 4);   // 8-bf16 slot in K
            bf16x8 af[4], bfr[4];
            #pragma unroll
            for (int m = 0; m < 4; ++m) {
                int row = wr * 64 + m * 16 + row_in_l;
                af[m] = *reinterpret_cast<const bf16x8*>(
                    &As[row * BK + ((kslot ^ (row & 7)) * 8)]);
            }
            #pragma unroll
            for (int n = 0; n < 4; ++n) {
                int row = wc * 64 + n * 16 + row_in_l;
                bfr[n] = *reinterpret_cast<const bf16x8*>(
                    &Bs[row * BK + ((kslot ^ (row & 7)) * 8)]);
            }
            #pragma unroll
            for (int m = 0; m < 4; ++m)
                #pragma unroll
                for (int n = 0; n < 4; ++n)
                    acc[m][n] = __builtin_amdgcn_mfma_f32_16x16x32_bf16(
                        af[m], bfr[n], acc[m][n], 0, 0, 0);
        }

        __syncthreads();
    }

    // ---- epilogue: C/D layout col=lane&15, row=(lane>>4)*4+reg ----
    const int cl = lane & 15;
    const int rq = lane >> 4;
    #pragma unroll
    for (int m = 0; m < 4; ++m) {
        #pragma unroll
        for (int n = 0; n < 4; ++n) {
            int col = n0 + wc * 64 + n * 16 + cl;
            #pragma unroll
            for (int r = 0; r < 4; ++r) {
                int row = m0 + wr * 64 + m * 16 + rq * 4 + r;
                out[(size_t)row * N_DIM + col] = acc[m][n][r];
            }
        }
    }
}

extern "C" void kernel_launch(void* const* d_in, const int* in_sizes, int n_in,
                              void* d_out, int out_size, void* d_ws, size_t ws_size,
                              hipStream_t stream) {
    const float*        x      = (const float*)d_in[0];
    const unsigned int* qw     = (const unsigned int*)d_in[1];
    const float*        scales = (const float*)d_in[2];
    const int*          qzeros = (const int*)d_in[3];
    // d_in[4] = g_idx (int64): known pattern g(k) = k/128, folded into kernel.
    float* out = (float*)d_out;

    dim3 grid(M_DIM / BM, N_DIM / BN);   // 64 x 86
    TurboQuantLinear_gemm_dq<<<grid, dim3(256), 0, stream>>>(x, qw, scales, qzeros, out);
}

// Round 2
// 823.455 us; speedup vs baseline: 1.6529x; 1.6529x over previous
//
#include <hip/hip_runtime.h>
#include <hip/hip_bf16.h>

typedef __bf16 bf16x8 __attribute__((ext_vector_type(8)));
typedef float f32x4 __attribute__((ext_vector_type(4)));

#define M_DIM 8192
#define K_DIM 4096
#define N_DIM 11008
#define KW 512      // K/8 ints per qweight row
#define NG 32

#define BM 128
#define BN 128
#define BK 64
#define KSTEPS (K_DIM / BK)   // 64

#define GLOAD_LDS16(g, l) \
  __builtin_amdgcn_global_load_lds((const __attribute__((address_space(1))) void*)(g), \
                                   (__attribute__((address_space(3))) void*)(l), 16, 0, 0)

// ---------------- prepass 1: x fp32 -> bf16 ----------------
__global__ __launch_bounds__(256) void cvt_x_bf16(
    const float* __restrict__ x, __bf16* __restrict__ xb)
{
    size_t i = (size_t)blockIdx.x * 256 + threadIdx.x;   // octet index, exact grid
    const float4* s = reinterpret_cast<const float4*>(x) + i * 2;
    float4 f0 = s[0];
    float4 f1 = s[1];
    bf16x8 v;
    v[0] = (__bf16)f0.x; v[1] = (__bf16)f0.y; v[2] = (__bf16)f0.z; v[3] = (__bf16)f0.w;
    v[4] = (__bf16)f1.x; v[5] = (__bf16)f1.y; v[6] = (__bf16)f1.z; v[7] = (__bf16)f1.w;
    *reinterpret_cast<bf16x8*>(xb + i * 8) = v;
}

// ---------------- prepass 2: dequant int4 -> bf16 ----------------
__global__ __launch_bounds__(256) void dequant_w_bf16(
    const unsigned int* __restrict__ qw, const float* __restrict__ sc,
    const int* __restrict__ qz, __bf16* __restrict__ wb)
{
    size_t idx = (size_t)blockIdx.x * 256 + threadIdx.x;  // one int32 each, exact grid
    unsigned int q = qw[idx];
    int row = (int)(idx >> 9);          // /512
    int g   = ((int)idx & 511) >> 4;    // (w*8)/128
    float s  = sc[row * NG + g];
    float zs = (float)qz[row * NG + g] * s;
    bf16x8 v;
    #pragma unroll
    for (int j = 0; j < 8; ++j)
        v[j] = (__bf16)((float)((q >> (4 * j)) & 15u) * s - zs);
    *reinterpret_cast<bf16x8*>(wb + idx * 8) = v;
}

// ---------------- main: bf16 GEMM, m97 structure ----------------
// A: [M][K] bf16 (ws), B: [N][K] bf16 (ws), out: [M][N] fp32
__global__ __launch_bounds__(256) void gemm_bf16_ws(
    const __bf16* __restrict__ A, const __bf16* __restrict__ B,
    float* __restrict__ out)
{
    __shared__ __attribute__((aligned(16))) __bf16 As[BM * BK];  // 16 KiB
    __shared__ __attribute__((aligned(16))) __bf16 Bs[BN * BK];  // 16 KiB

    const int t    = threadIdx.x;
    const int lane = t & 63;
    const int wave = t >> 6;
    const int wr   = wave >> 1;
    const int wc   = wave & 1;
    const int m0   = blockIdx.x * BM;
    const int n0   = blockIdx.y * BN;

    f32x4 acc[4][4] = {};

    // stage one K-step tile: linear LDS dest (wave-uniform base, HW adds lane*16),
    // inverse-swizzled global source: slot_src = (lane&7) ^ (row&7)
    auto stage = [&](int k0) {
        #pragma unroll
        for (int i = 0; i < 4; ++i) {
            int row  = i * 32 + wave * 8 + (lane >> 3);
            int slot = (lane & 7) ^ (row & 7);
            GLOAD_LDS16(&A[(size_t)(m0 + row) * K_DIM + k0 + slot * 8],
                        &As[i * 2048 + wave * 512]);
        }
        #pragma unroll
        for (int i = 0; i < 4; ++i) {
            int row  = i * 32 + wave * 8 + (lane >> 3);
            int slot = (lane & 7) ^ (row & 7);
            GLOAD_LDS16(&B[(size_t)(n0 + row) * K_DIM + k0 + slot * 8],
                        &Bs[i * 2048 + wave * 512]);
        }
    };

    stage(0);
    const int rl = lane & 15;
    for (int kt = 0; kt < KSTEPS; ++kt) {
        __syncthreads();   // drains vmcnt(0): staged tile visible

        #pragma unroll
        for (int kk = 0; kk < 2; ++kk) {
            const int kslot = kk * 4 + (lane >> 4);
            bf16x8 af[4], bfr[4];
            #pragma unroll
            for (int m = 0; m < 4; ++m) {
                int row = wr * 64 + m * 16 + rl;
                af[m] = *reinterpret_cast<const bf16x8*>(
                    &As[row * BK + ((kslot ^ (row & 7)) * 8)]);
            }
            #pragma unroll
            for (int n = 0; n < 4; ++n) {
                int row = wc * 64 + n * 16 + rl;
                bfr[n] = *reinterpret_cast<const bf16x8*>(
                    &Bs[row * BK + ((kslot ^ (row & 7)) * 8)]);
            }
            #pragma unroll
            for (int m = 0; m < 4; ++m)
                #pragma unroll
                for (int n = 0; n < 4; ++n)
                    acc[m][n] = __builtin_amdgcn_mfma_f32_16x16x32_bf16(
                        af[m], bfr[n], acc[m][n], 0, 0, 0);
        }

        if (kt + 1 < KSTEPS) {
            __syncthreads();          // all reads done before overwrite
            stage((kt + 1) * BK);
        }
    }

    // epilogue: C/D layout col=lane&15, row=(lane>>4)*4+reg
    const int cl = lane & 15;
    const int rq = lane >> 4;
    #pragma unroll
    for (int m = 0; m < 4; ++m) {
        #pragma unroll
        for (int n = 0; n < 4; ++n) {
            int col = n0 + wc * 64 + n * 16 + cl;
            #pragma unroll
            for (int r = 0; r < 4; ++r) {
                int row = m0 + wr * 64 + m * 16 + rq * 4 + r;
                out[(size_t)row * N_DIM + col] = acc[m][n][r];
            }
        }
    }
}

// ---------------- fallback: round-1 fused kernel ----------------
__global__ __launch_bounds__(256) void TurboQuantLinear_gemm_dq(
    const float* __restrict__ x,
    const unsigned int* __restrict__ qw,
    const float* __restrict__ scales,
    const int* __restrict__ qzeros,
    float* __restrict__ out)
{
    __shared__ __bf16 As[BM * BK];
    __shared__ __bf16 Bs[BN * BK];

    const int t    = threadIdx.x;
    const int lane = t & 63;
    const int wave = t >> 6;
    const int wr   = wave >> 1;
    const int wc   = wave & 1;
    const int m0 = blockIdx.x * BM;
    const int n0 = blockIdx.y * BN;

    f32x4 acc[4][4] = {};

    for (int kt = 0; kt < KSTEPS; ++kt) {
        const int k0 = kt * BK;
        const int g  = k0 >> 7;

        #pragma unroll
        for (int i = 0; i < 4; ++i) {
            int o  = t + i * 256;
            int r  = o >> 3;
            int c8 = o & 7;
            const float4* src = reinterpret_cast<const float4*>(
                &x[(size_t)(m0 + r) * K_DIM + k0 + c8 * 8]);
            float4 f0 = src[0];
            float4 f1 = src[1];
            bf16x8 v;
            v[0] = (__bf16)f0.x; v[1] = (__bf16)f0.y; v[2] = (__bf16)f0.z; v[3] = (__bf16)f0.w;
            v[4] = (__bf16)f1.x; v[5] = (__bf16)f1.y; v[6] = (__bf16)f1.z; v[7] = (__bf16)f1.w;
            int slot = c8 ^ (r & 7);
            *reinterpret_cast<bf16x8*>(&As[r * BK + slot * 8]) = v;
        }

        const int kw0 = kt * 8;
        #pragma unroll
        for (int i = 0; i < 4; ++i) {
            int idx = t + i * 256;
            int r   = idx >> 3;
            int w   = idx & 7;
            unsigned int q = qw[(size_t)(n0 + r) * KW + kw0 + w];
            float s  = scales[(n0 + r) * NG + g];
            float z  = (float)qzeros[(n0 + r) * NG + g];
            float zs = z * s;
            bf16x8 v;
            #pragma unroll
            for (int j = 0; j < 8; ++j) {
                float val = (float)((q >> (4 * j)) & 15u) * s - zs;
                v[j] = (__bf16)val;
            }
            int slot = w ^ (r & 7);
            *reinterpret_cast<bf16x8*>(&Bs[r * BK + slot * 8]) = v;
        }

        __syncthreads();

        const int row_in_l = lane & 15;
        #pragma unroll
        for (int kk = 0; kk < 2; ++kk) {
            const int kslot = kk * 4 + (lane >> 4);
            bf16x8 af[4], bfr[4];
            #pragma unroll
            for (int m = 0; m < 4; ++m) {
                int row = wr * 64 + m * 16 + row_in_l;
                af[m] = *reinterpret_cast<const bf16x8*>(
                    &As[row * BK + ((kslot ^ (row & 7)) * 8)]);
            }
            #pragma unroll
            for (int n = 0; n < 4; ++n) {
                int row = wc * 64 + n * 16 + row_in_l;
                bfr[n] = *reinterpret_cast<const bf16x8*>(
                    &Bs[row * BK + ((kslot ^ (row & 7)) * 8)]);
            }
            #pragma unroll
            for (int m = 0; m < 4; ++m)
                #pragma unroll
                for (int n = 0; n < 4; ++n)
                    acc[m][n] = __builtin_amdgcn_mfma_f32_16x16x32_bf16(
                        af[m], bfr[n], acc[m][n], 0, 0, 0);
        }

        __syncthreads();
    }

    const int cl = lane & 15;
    const int rq = lane >> 4;
    #pragma unroll
    for (int m = 0; m < 4; ++m) {
        #pragma unroll
        for (int n = 0; n < 4; ++n) {
            int col = n0 + wc * 64 + n * 16 + cl;
            #pragma unroll
            for (int r = 0; r < 4; ++r) {
                int row = m0 + wr * 64 + m * 16 + rq * 4 + r;
                out[(size_t)row * N_DIM + col] = acc[m][n][r];
            }
        }
    }
}

extern "C" void kernel_launch(void* const* d_in, const int* in_sizes, int n_in,
                              void* d_out, int out_size, void* d_ws, size_t ws_size,
                              hipStream_t stream) {
    const float*        x      = (const float*)d_in[0];
    const unsigned int* qw     = (const unsigned int*)d_in[1];
    const float*        scales = (const float*)d_in[2];
    const int*          qzeros = (const int*)d_in[3];
    // d_in[4] = g_idx (int64): known pattern g(k) = k/128, folded into kernels.
    float* out = (float*)d_out;

    const size_t xb_bytes = (size_t)M_DIM * K_DIM * sizeof(__bf16);  // 64 MiB
    const size_t wb_bytes = (size_t)N_DIM * K_DIM * sizeof(__bf16);  // 86 MiB

    if (ws_size >= xb_bytes + wb_bytes) {
        __bf16* xb = (__bf16*)d_ws;
        __bf16* wb = (__bf16*)((char*)d_ws + xb_bytes);

        // prepass 1: 8192*4096/8 = 4,194,304 octets / 256 = 16384 blocks
        cvt_x_bf16<<<dim3(16384), dim3(256), 0, stream>>>(x, xb);
        // prepass 2: 11008*512 = 5,636,096 ints / 256 = 22016 blocks
        dequant_w_bf16<<<dim3(22016), dim3(256), 0, stream>>>(qw, scales, qzeros, wb);

        dim3 grid(M_DIM / BM, N_DIM / BN);   // 64 x 86
        gemm_bf16_ws<<<grid, dim3(256), 0, stream>>>(xb, wb, out);
    } else {
        dim3 grid(M_DIM / BM, N_DIM / BN);
        TurboQuantLinear_gemm_dq<<<grid, dim3(256), 0, stream>>>(x, qw, scales, qzeros, out);
    }
}

// Round 3
// 776.963 us; speedup vs baseline: 1.7518x; 1.0598x over previous
//
#include <hip/hip_runtime.h>
#include <hip/hip_bf16.h>

typedef __bf16 bf16x8 __attribute__((ext_vector_type(8)));
typedef float f32x4 __attribute__((ext_vector_type(4)));

#define M_DIM 8192
#define K_DIM 4096
#define N_DIM 11008
#define KW 512
#define NG 32
#define NT 64            // K-tiles of 64

#define GLOAD_LDS16(g, l) \
  __builtin_amdgcn_global_load_lds((const __attribute__((address_space(1))) void*)(g), \
                                   (__attribute__((address_space(3))) void*)(l), 16, 0, 0)

// ---------------- prepass 1: x fp32 -> bf16 ----------------
__global__ __launch_bounds__(256) void cvt_x_bf16(
    const float* __restrict__ x, __bf16* __restrict__ xb)
{
    size_t i = (size_t)blockIdx.x * 256 + threadIdx.x;
    const float4* s = reinterpret_cast<const float4*>(x) + i * 2;
    float4 f0 = s[0];
    float4 f1 = s[1];
    bf16x8 v;
    v[0] = (__bf16)f0.x; v[1] = (__bf16)f0.y; v[2] = (__bf16)f0.z; v[3] = (__bf16)f0.w;
    v[4] = (__bf16)f1.x; v[5] = (__bf16)f1.y; v[6] = (__bf16)f1.z; v[7] = (__bf16)f1.w;
    *reinterpret_cast<bf16x8*>(xb + i * 8) = v;
}

// ---------------- prepass 2: dequant int4 -> bf16 ----------------
__global__ __launch_bounds__(256) void dequant_w_bf16(
    const unsigned int* __restrict__ qw, const float* __restrict__ sc,
    const int* __restrict__ qz, __bf16* __restrict__ wb)
{
    size_t idx = (size_t)blockIdx.x * 256 + threadIdx.x;
    unsigned int q = qw[idx];
    int row = (int)(idx >> 9);
    int g   = ((int)idx & 511) >> 4;
    float s  = sc[row * NG + g];
    float zs = (float)qz[row * NG + g] * s;
    bf16x8 v;
    #pragma unroll
    for (int j = 0; j < 8; ++j)
        v[j] = (__bf16)((float)((q >> (4 * j)) & 15u) * s - zs);
    *reinterpret_cast<bf16x8*>(wb + idx * 8) = v;
}

// ---------------- main: 256x256 8-phase bf16 GEMM ----------------
// lds[buf][op(0=A,1=B)][ks][row 0..255][col 0..31 bf16]; 128 KiB total.
// swizzle: physical 16B-slot = logical_slot ^ ((row>>1)&3)

// stage one 16-KiB sub-tile (2 x global_load_lds per wave)
#define STAGE_SUB(SBUF, SOP, SKS, STILE)                                          \
  do {                                                                            \
    _Pragma("unroll")                                                             \
    for (int j_ = 0; j_ < 2; ++j_) {                                              \
      int srow_ = j_ * 128 + w * 16 + (lane >> 2);                                \
      const __bf16* sp_ = ((SOP) == 0)                                            \
        ? Ag + (size_t)(m0 + srow_) * K_DIM + (STILE) * 64 + (SKS) * 32 + sslotg * 8 \
        : Bg + (size_t)(n0 + srow_) * K_DIM + (STILE) * 64 + (SKS) * 32 + sslotg * 8; \
      GLOAD_LDS16(sp_, &lds[SBUF][SOP][SKS][j_ * 128 + w * 16][0]);               \
    }                                                                             \
  } while (0)

#define PHASE(BUF, MH, KS, LOADB, SBUF, SOP, SKS, STILE, DO_VM)                   \
  do {                                                                            \
    bf16x8 af_[4];                                                                \
    _Pragma("unroll")                                                             \
    for (int m_ = 0; m_ < 4; ++m_) {                                              \
      int row_ = wm * 128 + (MH) * 64 + m_ * 16 + lane16;                         \
      af_[m_] = *reinterpret_cast<const bf16x8*>(&lds[BUF][0][KS][row_][colElem]);\
    }                                                                             \
    if (LOADB) {                                                                  \
      _Pragma("unroll")                                                           \
      for (int n_ = 0; n_ < 4; ++n_) {                                            \
        int row_ = wn * 64 + n_ * 16 + lane16;                                    \
        bcur[n_] = *reinterpret_cast<const bf16x8*>(&lds[BUF][1][KS][row_][colElem]);\
      }                                                                           \
    }                                                                             \
    STAGE_SUB(SBUF, SOP, SKS, STILE);                                             \
    __builtin_amdgcn_s_barrier();                                                 \
    __builtin_amdgcn_s_setprio(1);                                                \
    _Pragma("unroll")                                                             \
    for (int m_ = 0; m_ < 4; ++m_)                                                \
      _Pragma("unroll")                                                           \
      for (int n_ = 0; n_ < 4; ++n_)                                              \
        acc[(MH) * 4 + m_][n_] = __builtin_amdgcn_mfma_f32_16x16x32_bf16(         \
            af_[m_], bcur[n_], acc[(MH) * 4 + m_][n_], 0, 0, 0);                  \
    __builtin_amdgcn_s_setprio(0);                                                \
    if (DO_VM) asm volatile("s_waitcnt vmcnt(10)" ::: "memory");                  \
    __builtin_amdgcn_s_barrier();                                                 \
  } while (0)

__global__ __launch_bounds__(512, 2) void gemm_bf16_8phase(
    const __bf16* __restrict__ Ag, const __bf16* __restrict__ Bg,
    float* __restrict__ out)
{
    __shared__ __attribute__((aligned(16))) __bf16 lds[2][2][2][256][32];

    const int t      = threadIdx.x;
    const int lane   = t & 63;
    const int w      = t >> 6;        // wave 0..7
    const int wm     = w >> 2;        // 0..1  -> M band of 128
    const int wn     = w & 3;         // 0..3  -> N band of 64
    const int lane16 = lane & 15;
    const int psl    = (lane >> 4) ^ ((lane16 >> 1) & 3);   // read physical slot
    const int colElem = psl * 8;
    const int sslotg = (lane & 3) ^ ((lane >> 3) & 3);      // stage source slot

    // XCD-aware swizzle: 1376 wgs = 8 XCDs x 172
    int bid = blockIdx.x;
    int wg  = (bid & 7) * 172 + (bid >> 3);
    int bm  = wg / 43;
    int bn  = wg - bm * 43;
    const int m0 = bm * 256;
    const int n0 = bn * 256;

    f32x4 acc[8][4] = {};
    bf16x8 bcur[4];

    // prologue: buf0 <- tile0 complete; buf1 <- tile1 {A.k0, B.k0, B.k1}
    STAGE_SUB(0, 0, 0, 0);
    STAGE_SUB(0, 1, 0, 0);
    STAGE_SUB(0, 0, 1, 0);
    STAGE_SUB(0, 1, 1, 0);
    STAGE_SUB(1, 0, 0, 1);
    STAGE_SUB(1, 1, 0, 1);
    STAGE_SUB(1, 1, 1, 1);
    asm volatile("s_waitcnt vmcnt(0)" ::: "memory");
    __builtin_amdgcn_s_barrier();

    for (int it = 0; it < NT / 2; ++it) {
        const int t1 = (it * 2 + 1) & (NT - 1);   // buf1 A.k1 (real data always)
        const int t2 = (it * 2 + 2) & (NT - 1);   // buf0 tiles (garbage-safe at last iter)
        const int t3 = (it * 2 + 3) & (NT - 1);   // buf1 tiles

        //    read-buf mh ks loadB | stage-buf op ks tile | vmcnt?
        PHASE(0,       0, 0, 1,      1,       0, 1, t1,     0);   // P1
        PHASE(0,       1, 0, 0,      0,       1, 0, t2,     1);   // P2
        PHASE(0,       0, 1, 1,      0,       0, 0, t2,     0);   // P3
        PHASE(0,       1, 1, 0,      0,       1, 1, t2,     1);   // P4
        PHASE(1,       0, 0, 1,      0,       0, 1, t2,     0);   // P5
        PHASE(1,       1, 0, 0,      1,       1, 0, t3,     1);   // P6
        PHASE(1,       0, 1, 1,      1,       0, 0, t3,     0);   // P7
        PHASE(1,       1, 1, 0,      1,       1, 1, t3,     1);   // P8
    }

    asm volatile("s_waitcnt vmcnt(0)" ::: "memory");   // drain tail garbage stages

    // epilogue: C/D layout col=lane&15, row=(lane>>4)*4+r
    const int cl = lane & 15;
    const int rq = lane >> 4;
    #pragma unroll
    for (int mi = 0; mi < 8; ++mi) {
        #pragma unroll
        for (int n = 0; n < 4; ++n) {
            int col = n0 + wn * 64 + n * 16 + cl;
            #pragma unroll
            for (int r = 0; r < 4; ++r) {
                int row = m0 + wm * 128 + (mi >> 2) * 64 + (mi & 3) * 16 + rq * 4 + r;
                out[(size_t)row * N_DIM + col] = acc[mi][n][r];
            }
        }
    }
}

// ---------------- fallback: round-1 fused kernel (128^2) ----------------
#define BM 128
#define BN 128
#define BK 64
#define KSTEPS (K_DIM / BK)

__global__ __launch_bounds__(256) void TurboQuantLinear_gemm_dq(
    const float* __restrict__ x,
    const unsigned int* __restrict__ qw,
    const float* __restrict__ scales,
    const int* __restrict__ qzeros,
    float* __restrict__ out)
{
    __shared__ __bf16 As[BM * BK];
    __shared__ __bf16 Bs[BN * BK];

    const int t    = threadIdx.x;
    const int lane = t & 63;
    const int wave = t >> 6;
    const int wr   = wave >> 1;
    const int wc   = wave & 1;
    const int m0 = blockIdx.x * BM;
    const int n0 = blockIdx.y * BN;

    f32x4 acc[4][4] = {};

    for (int kt = 0; kt < KSTEPS; ++kt) {
        const int k0 = kt * BK;
        const int g  = k0 >> 7;

        #pragma unroll
        for (int i = 0; i < 4; ++i) {
            int o  = t + i * 256;
            int r  = o >> 3;
            int c8 = o & 7;
            const float4* src = reinterpret_cast<const float4*>(
                &x[(size_t)(m0 + r) * K_DIM + k0 + c8 * 8]);
            float4 f0 = src[0];
            float4 f1 = src[1];
            bf16x8 v;
            v[0] = (__bf16)f0.x; v[1] = (__bf16)f0.y; v[2] = (__bf16)f0.z; v[3] = (__bf16)f0.w;
            v[4] = (__bf16)f1.x; v[5] = (__bf16)f1.y; v[6] = (__bf16)f1.z; v[7] = (__bf16)f1.w;
            int slot = c8 ^ (r & 7);
            *reinterpret_cast<bf16x8*>(&As[r * BK + slot * 8]) = v;
        }

        const int kw0 = kt * 8;
        #pragma unroll
        for (int i = 0; i < 4; ++i) {
            int idx = t + i * 256;
            int r   = idx >> 3;
            int wq  = idx & 7;
            unsigned int q = qw[(size_t)(n0 + r) * KW + kw0 + wq];
            float s  = scales[(n0 + r) * NG + g];
            float z  = (float)qzeros[(n0 + r) * NG + g];
            float zs = z * s;
            bf16x8 v;
            #pragma unroll
            for (int j = 0; j < 8; ++j) {
                float val = (float)((q >> (4 * j)) & 15u) * s - zs;
                v[j] = (__bf16)val;
            }
            int slot = wq ^ (r & 7);
            *reinterpret_cast<bf16x8*>(&Bs[r * BK + slot * 8]) = v;
        }

        __syncthreads();

        const int row_in_l = lane & 15;
        #pragma unroll
        for (int kk = 0; kk < 2; ++kk) {
            const int kslot = kk * 4 + (lane >> 4);
            bf16x8 af[4], bfr[4];
            #pragma unroll
            for (int m = 0; m < 4; ++m) {
                int row = wr * 64 + m * 16 + row_in_l;
                af[m] = *reinterpret_cast<const bf16x8*>(
                    &As[row * BK + ((kslot ^ (row & 7)) * 8)]);
            }
            #pragma unroll
            for (int n = 0; n < 4; ++n) {
                int row = wc * 64 + n * 16 + row_in_l;
                bfr[n] = *reinterpret_cast<const bf16x8*>(
                    &Bs[row * BK + ((kslot ^ (row & 7)) * 8)]);
            }
            #pragma unroll
            for (int m = 0; m < 4; ++m)
                #pragma unroll
                for (int n = 0; n < 4; ++n)
                    acc[m][n] = __builtin_amdgcn_mfma_f32_16x16x32_bf16(
                        af[m], bfr[n], acc[m][n], 0, 0, 0);
        }

        __syncthreads();
    }

    const int cl = lane & 15;
    const int rq = lane >> 4;
    #pragma unroll
    for (int m = 0; m < 4; ++m) {
        #pragma unroll
        for (int n = 0; n < 4; ++n) {
            int col = n0 + wc * 64 + n * 16 + cl;
            #pragma unroll
            for (int r = 0; r < 4; ++r) {
                int row = m0 + wr * 64 + m * 16 + rq * 4 + r;
                out[(size_t)row * N_DIM + col] = acc[m][n][r];
            }
        }
    }
}

extern "C" void kernel_launch(void* const* d_in, const int* in_sizes, int n_in,
                              void* d_out, int out_size, void* d_ws, size_t ws_size,
                              hipStream_t stream) {
    const float*        x      = (const float*)d_in[0];
    const unsigned int* qw     = (const unsigned int*)d_in[1];
    const float*        scales = (const float*)d_in[2];
    const int*          qzeros = (const int*)d_in[3];
    // d_in[4] = g_idx (int64): known pattern g(k) = k/128, folded into kernels.
    float* out = (float*)d_out;

    const size_t xb_bytes = (size_t)M_DIM * K_DIM * sizeof(__bf16);  // 64 MiB
    const size_t wb_bytes = (size_t)N_DIM * K_DIM * sizeof(__bf16);  // 86 MiB

    if (ws_size >= xb_bytes + wb_bytes) {
        __bf16* xb = (__bf16*)d_ws;
        __bf16* wb = (__bf16*)((char*)d_ws + xb_bytes);

        cvt_x_bf16<<<dim3(16384), dim3(256), 0, stream>>>(x, xb);
        dequant_w_bf16<<<dim3(22016), dim3(256), 0, stream>>>(qw, scales, qzeros, wb);

        // 32 x 43 = 1376 workgroups, XCD-swizzled inside the kernel
        gemm_bf16_8phase<<<dim3(1376), dim3(512), 0, stream>>>(xb, wb, out);
    } else {
        dim3 grid(M_DIM / BM, N_DIM / BN);
        TurboQuantLinear_gemm_dq<<<grid, dim3(256), 0, stream>>>(x, qw, scales, qzeros, out);
    }
}

// Round 5
// 761.013 us; speedup vs baseline: 1.7885x; 1.0210x over previous
//
#include <hip/hip_runtime.h>
#include <hip/hip_bf16.h>

typedef __bf16 bf16x8 __attribute__((ext_vector_type(8)));
typedef float f32x4 __attribute__((ext_vector_type(4)));
typedef float f32x4v __attribute__((ext_vector_type(4)));   // native vec for nontemporal builtins

#define M_DIM 8192
#define K_DIM 4096
#define N_DIM 11008
#define KW 512
#define NG 32
#define NT 64            // K-tiles of 64

#define GLOAD_LDS16(g, l) \
  __builtin_amdgcn_global_load_lds((const __attribute__((address_space(1))) void*)(g), \
                                   (__attribute__((address_space(3))) void*)(l), 16, 0, 0)

// ---------------- prepass 1: x fp32 -> bf16 ----------------
__global__ __launch_bounds__(256) void cvt_x_bf16(
    const float* __restrict__ x, __bf16* __restrict__ xb)
{
    size_t i = (size_t)blockIdx.x * 256 + threadIdx.x;
    const f32x4v* s = reinterpret_cast<const f32x4v*>(x) + i * 2;
    f32x4v f0 = __builtin_nontemporal_load(s);       // x read exactly once
    f32x4v f1 = __builtin_nontemporal_load(s + 1);
    bf16x8 v;
    v[0] = (__bf16)f0[0]; v[1] = (__bf16)f0[1]; v[2] = (__bf16)f0[2]; v[3] = (__bf16)f0[3];
    v[4] = (__bf16)f1[0]; v[5] = (__bf16)f1[1]; v[6] = (__bf16)f1[2]; v[7] = (__bf16)f1[3];
    *reinterpret_cast<bf16x8*>(xb + i * 8) = v;      // xb cached: GEMM re-reads it
}

// ---------------- prepass 2: dequant int4 -> bf16 ----------------
__global__ __launch_bounds__(256) void dequant_w_bf16(
    const unsigned int* __restrict__ qw, const float* __restrict__ sc,
    const int* __restrict__ qz, __bf16* __restrict__ wb)
{
    size_t idx = (size_t)blockIdx.x * 256 + threadIdx.x;
    unsigned int q = __builtin_nontemporal_load(qw + idx);   // read exactly once
    int row = (int)(idx >> 9);
    int g   = ((int)idx & 511) >> 4;
    float s  = sc[row * NG + g];
    float zs = (float)qz[row * NG + g] * s;
    bf16x8 v;
    #pragma unroll
    for (int j = 0; j < 8; ++j)
        v[j] = (__bf16)((float)((q >> (4 * j)) & 15u) * s - zs);
    *reinterpret_cast<bf16x8*>(wb + idx * 8) = v;    // wb cached: GEMM re-reads it
}

// ---------------- main: 256x256 8-phase bf16 GEMM ----------------
// lds[buf][op(0=A,1=B)][ks][row 0..255][col 0..31 bf16]; 128 KiB total.
// swizzle: physical 16B-slot = logical_slot ^ ((row>>1)&3)

#define STAGE_SUB(SBUF, SOP, SKS, STILE)                                          \
  do {                                                                            \
    _Pragma("unroll")                                                             \
    for (int j_ = 0; j_ < 2; ++j_) {                                              \
      int srow_ = j_ * 128 + w * 16 + (lane >> 2);                                \
      const __bf16* sp_ = ((SOP) == 0)                                            \
        ? Ag + (size_t)(m0 + srow_) * K_DIM + (STILE) * 64 + (SKS) * 32 + sslotg * 8 \
        : Bg + (size_t)(n0 + srow_) * K_DIM + (STILE) * 64 + (SKS) * 32 + sslotg * 8; \
      GLOAD_LDS16(sp_, &lds[SBUF][SOP][SKS][j_ * 128 + w * 16][0]);               \
    }                                                                             \
  } while (0)

#define PHASE(BUF, MH, KS, LOADB, SBUF, SOP, SKS, STILE, DO_VM)                   \
  do {                                                                            \
    bf16x8 af_[4];                                                                \
    _Pragma("unroll")                                                             \
    for (int m_ = 0; m_ < 4; ++m_) {                                              \
      int row_ = wm * 128 + (MH) * 64 + m_ * 16 + lane16;                         \
      af_[m_] = *reinterpret_cast<const bf16x8*>(&lds[BUF][0][KS][row_][colElem]);\
    }                                                                             \
    if (LOADB) {                                                                  \
      _Pragma("unroll")                                                           \
      for (int n_ = 0; n_ < 4; ++n_) {                                            \
        int row_ = wn * 64 + n_ * 16 + lane16;                                    \
        bcur[n_] = *reinterpret_cast<const bf16x8*>(&lds[BUF][1][KS][row_][colElem]);\
      }                                                                           \
    }                                                                             \
    STAGE_SUB(SBUF, SOP, SKS, STILE);                                             \
    __builtin_amdgcn_s_barrier();                                                 \
    __builtin_amdgcn_s_setprio(1);                                                \
    _Pragma("unroll")                                                             \
    for (int m_ = 0; m_ < 4; ++m_)                                                \
      _Pragma("unroll")                                                           \
      for (int n_ = 0; n_ < 4; ++n_)                                              \
        acc[(MH) * 4 + m_][n_] = __builtin_amdgcn_mfma_f32_16x16x32_bf16(         \
            af_[m_], bcur[n_], acc[(MH) * 4 + m_][n_], 0, 0, 0);                  \
    __builtin_amdgcn_s_setprio(0);                                                \
    if (DO_VM) asm volatile("s_waitcnt vmcnt(10)" ::: "memory");                  \
    __builtin_amdgcn_s_barrier();                                                 \
  } while (0)

__global__ __launch_bounds__(512, 2) void gemm_bf16_8phase(
    const __bf16* __restrict__ Ag, const __bf16* __restrict__ Bg,
    float* __restrict__ out)
{
    __shared__ __attribute__((aligned(16))) __bf16 lds[2][2][2][256][32];

    const int t      = threadIdx.x;
    const int lane   = t & 63;
    const int w      = t >> 6;
    const int wm     = w >> 2;
    const int wn     = w & 3;
    const int lane16 = lane & 15;
    const int psl    = (lane >> 4) ^ ((lane16 >> 1) & 3);
    const int colElem = psl * 8;
    const int sslotg = (lane & 3) ^ ((lane >> 3) & 3);

    int bid = blockIdx.x;
    int wg  = (bid & 7) * 172 + (bid >> 3);
    int bm  = wg / 43;
    int bn  = wg - bm * 43;
    const int m0 = bm * 256;
    const int n0 = bn * 256;

    f32x4 acc[8][4] = {};
    bf16x8 bcur[4];

    STAGE_SUB(0, 0, 0, 0);
    STAGE_SUB(0, 1, 0, 0);
    STAGE_SUB(0, 0, 1, 0);
    STAGE_SUB(0, 1, 1, 0);
    STAGE_SUB(1, 0, 0, 1);
    STAGE_SUB(1, 1, 0, 1);
    STAGE_SUB(1, 1, 1, 1);
    asm volatile("s_waitcnt vmcnt(0)" ::: "memory");
    __builtin_amdgcn_s_barrier();

    for (int it = 0; it < NT / 2; ++it) {
        const int t1 = (it * 2 + 1) & (NT - 1);
        const int t2 = (it * 2 + 2) & (NT - 1);
        const int t3 = (it * 2 + 3) & (NT - 1);

        //    read-buf mh ks loadB | stage-buf op ks tile | vmcnt?
        PHASE(0,       0, 0, 1,      1,       0, 1, t1,     0);   // P1
        PHASE(0,       1, 0, 0,      0,       1, 0, t2,     1);   // P2
        PHASE(0,       0, 1, 1,      0,       0, 0, t2,     0);   // P3
        PHASE(0,       1, 1, 0,      0,       1, 1, t2,     1);   // P4
        PHASE(1,       0, 0, 1,      0,       0, 1, t2,     0);   // P5
        PHASE(1,       1, 0, 0,      1,       1, 0, t3,     1);   // P6
        PHASE(1,       0, 1, 1,      1,       0, 0, t3,     0);   // P7
        PHASE(1,       1, 1, 0,      1,       1, 1, t3,     1);   // P8
    }

    asm volatile("s_waitcnt vmcnt(0)" ::: "memory");

    // epilogue: non-temporal C stores — C is write-once, never re-read;
    // keeps the 354 MB write stream from evicting xb/wb out of LLC.
    const int cl = lane & 15;
    const int rq = lane >> 4;
    #pragma unroll
    for (int mi = 0; mi < 8; ++mi) {
        #pragma unroll
        for (int n = 0; n < 4; ++n) {
            int col = n0 + wn * 64 + n * 16 + cl;
            #pragma unroll
            for (int r = 0; r < 4; ++r) {
                int row = m0 + wm * 128 + (mi >> 2) * 64 + (mi & 3) * 16 + rq * 4 + r;
                __builtin_nontemporal_store(acc[mi][n][r],
                                            &out[(size_t)row * N_DIM + col]);
            }
        }
    }
}

// ---------------- fallback: round-1 fused kernel (128^2) ----------------
#define BM 128
#define BN 128
#define BK 64
#define KSTEPS (K_DIM / BK)

__global__ __launch_bounds__(256) void TurboQuantLinear_gemm_dq(
    const float* __restrict__ x,
    const unsigned int* __restrict__ qw,
    const float* __restrict__ scales,
    const int* __restrict__ qzeros,
    float* __restrict__ out)
{
    __shared__ __bf16 As[BM * BK];
    __shared__ __bf16 Bs[BN * BK];

    const int t    = threadIdx.x;
    const int lane = t & 63;
    const int wave = t >> 6;
    const int wr   = wave >> 1;
    const int wc   = wave & 1;
    const int m0 = blockIdx.x * BM;
    const int n0 = blockIdx.y * BN;

    f32x4 acc[4][4] = {};

    for (int kt = 0; kt < KSTEPS; ++kt) {
        const int k0 = kt * BK;
        const int g  = k0 >> 7;

        #pragma unroll
        for (int i = 0; i < 4; ++i) {
            int o  = t + i * 256;
            int r  = o >> 3;
            int c8 = o & 7;
            const float4* src = reinterpret_cast<const float4*>(
                &x[(size_t)(m0 + r) * K_DIM + k0 + c8 * 8]);
            float4 f0 = src[0];
            float4 f1 = src[1];
            bf16x8 v;
            v[0] = (__bf16)f0.x; v[1] = (__bf16)f0.y; v[2] = (__bf16)f0.z; v[3] = (__bf16)f0.w;
            v[4] = (__bf16)f1.x; v[5] = (__bf16)f1.y; v[6] = (__bf16)f1.z; v[7] = (__bf16)f1.w;
            int slot = c8 ^ (r & 7);
            *reinterpret_cast<bf16x8*>(&As[r * BK + slot * 8]) = v;
        }

        const int kw0 = kt * 8;
        #pragma unroll
        for (int i = 0; i < 4; ++i) {
            int idx = t + i * 256;
            int r   = idx >> 3;
            int wq  = idx & 7;
            unsigned int q = qw[(size_t)(n0 + r) * KW + kw0 + wq];
            float s  = scales[(n0 + r) * NG + g];
            float z  = (float)qzeros[(n0 + r) * NG + g];
            float zs = z * s;
            bf16x8 v;
            #pragma unroll
            for (int j = 0; j < 8; ++j) {
                float val = (float)((q >> (4 * j)) & 15u) * s - zs;
                v[j] = (__bf16)val;
            }
            int slot = wq ^ (r & 7);
            *reinterpret_cast<bf16x8*>(&Bs[r * BK + slot * 8]) = v;
        }

        __syncthreads();

        const int row_in_l = lane & 15;
        #pragma unroll
        for (int kk = 0; kk < 2; ++kk) {
            const int kslot = kk * 4 + (lane >> 4);
            bf16x8 af[4], bfr[4];
            #pragma unroll
            for (int m = 0; m < 4; ++m) {
                int row = wr * 64 + m * 16 + row_in_l;
                af[m] = *reinterpret_cast<const bf16x8*>(
                    &As[row * BK + ((kslot ^ (row & 7)) * 8)]);
            }
            #pragma unroll
            for (int n = 0; n < 4; ++n) {
                int row = wc * 64 + n * 16 + row_in_l;
                bfr[n] = *reinterpret_cast<const bf16x8*>(
                    &Bs[row * BK + ((kslot ^ (row & 7)) * 8)]);
            }
            #pragma unroll
            for (int m = 0; m < 4; ++m)
                #pragma unroll
                for (int n = 0; n < 4; ++n)
                    acc[m][n] = __builtin_amdgcn_mfma_f32_16x16x32_bf16(
                        af[m], bfr[n], acc[m][n], 0, 0, 0);
        }

        __syncthreads();
    }

    const int cl = lane & 15;
    const int rq = lane >> 4;
    #pragma unroll
    for (int m = 0; m < 4; ++m) {
        #pragma unroll
        for (int n = 0; n < 4; ++n) {
            int col = n0 + wc * 64 + n * 16 + cl;
            #pragma unroll
            for (int r = 0; r < 4; ++r) {
                int row = m0 + wr * 64 + m * 16 + rq * 4 + r;
                out[(size_t)row * N_DIM + col] = acc[m][n][r];
            }
        }
    }
}

extern "C" void kernel_launch(void* const* d_in, const int* in_sizes, int n_in,
                              void* d_out, int out_size, void* d_ws, size_t ws_size,
                              hipStream_t stream) {
    const float*        x      = (const float*)d_in[0];
    const unsigned int* qw     = (const unsigned int*)d_in[1];
    const float*        scales = (const float*)d_in[2];
    const int*          qzeros = (const int*)d_in[3];
    float* out = (float*)d_out;

    const size_t xb_bytes = (size_t)M_DIM * K_DIM * sizeof(__bf16);
    const size_t wb_bytes = (size_t)N_DIM * K_DIM * sizeof(__bf16);

    if (ws_size >= xb_bytes + wb_bytes) {
        __bf16* xb = (__bf16*)d_ws;
        __bf16* wb = (__bf16*)((char*)d_ws + xb_bytes);

        cvt_x_bf16<<<dim3(16384), dim3(256), 0, stream>>>(x, xb);
        dequant_w_bf16<<<dim3(22016), dim3(256), 0, stream>>>(qw, scales, qzeros, wb);

        gemm_bf16_8phase<<<dim3(1376), dim3(512), 0, stream>>>(xb, wb, out);
    } else {
        dim3 grid(M_DIM / BM, N_DIM / BN);
        TurboQuantLinear_gemm_dq<<<grid, dim3(256), 0, stream>>>(x, qw, scales, qzeros, out);
    }
}